// Round 1
// baseline (51.841 us; speedup 1.0000x reference)
//
#include <hip/hip_runtime.h>

#define NUM_EMB 100000
#define DIM 128
#define TILE_E 32

// Pass 1: WT[e][d] = W[d][e] + b[d]   (fused bias)
// W: [DIM][NUM_EMB] row-major, WT: [NUM_EMB][DIM] row-major.
// grid = NUM_EMB/TILE_E = 3125 blocks, 256 threads.
__global__ __launch_bounds__(256) void transpose_bias_kernel(
    const float* __restrict__ W, const float* __restrict__ b,
    float* __restrict__ WT) {
  __shared__ float tile[TILE_E][DIM + 1];  // +1 pad: write phase ~2-way (free), read phase stride-1
  const int t = threadIdx.x;
  const int e0 = blockIdx.x * TILE_E;

  // Load: 128 d-rows x 32 e = 1024 float4 (each float4 = 4 consecutive e for one d).
  // Coalesced: 8 lanes cover one 128B row segment.
#pragma unroll
  for (int k = 0; k < 4; ++k) {
    const int linear = k * 256 + t;       // 0..1023
    const int e4 = linear & 7;            // which float4 within the 32-e row
    const int d = linear >> 3;            // 0..127
    const float4 v = *reinterpret_cast<const float4*>(
        &W[(size_t)d * NUM_EMB + e0 + e4 * 4]);
    const float bias = b[d];
    tile[e4 * 4 + 0][d] = v.x + bias;
    tile[e4 * 4 + 1][d] = v.y + bias;
    tile[e4 * 4 + 2][d] = v.z + bias;
    tile[e4 * 4 + 3][d] = v.w + bias;
  }
  __syncthreads();

  // Store: 32 e-rows x 128 d, scalar 4B/lane, 256B/wave contiguous.
  // LDS read tile[e][d] with d consecutive per lane: conflict-free.
#pragma unroll
  for (int k = 0; k < 16; ++k) {
    const int linear = k * 256 + t;       // 0..4095
    const int d = linear & (DIM - 1);
    const int e = linear >> 7;            // 0..31
    WT[(size_t)(e0 + e) * DIM + d] = tile[e][d];
  }
}

// Pass 2: out[n][:] = WT[idx[n]][:]  — contiguous 512B row per lookup.
// 32 lanes per lookup, float4 per lane. 8 lookups per 256-thread block.
__global__ __launch_bounds__(256) void gather_rows_kernel(
    const int* __restrict__ idx, const float* __restrict__ WT,
    float* __restrict__ out, int n_lookups) {
  const int t = threadIdx.x;
  const int n = blockIdx.x * 8 + (t >> 5);
  const int q = t & 31;
  if (n >= n_lookups) return;
  const int e = idx[n];
  const float4 v = reinterpret_cast<const float4*>(WT)[(size_t)e * 32 + q];
  reinterpret_cast<float4*>(out)[(size_t)n * 32 + q] = v;
}

// Fallback (ws too small): direct scattered gather, correct but slow.
__global__ __launch_bounds__(256) void direct_gather_kernel(
    const int* __restrict__ idx, const float* __restrict__ W,
    const float* __restrict__ b, float* __restrict__ out, long total) {
  long gid = (long)blockIdx.x * 256 + threadIdx.x;
  const long stride = (long)gridDim.x * 256;
  for (; gid < total; gid += stride) {
    const int d = (int)(gid & (DIM - 1));
    const long n = gid >> 7;
    out[gid] = W[(size_t)d * NUM_EMB + idx[n]] + b[d];
  }
}

extern "C" void kernel_launch(void* const* d_in, const int* in_sizes, int n_in,
                              void* d_out, int out_size, void* d_ws,
                              size_t ws_size, hipStream_t stream) {
  const int* idx = (const int*)d_in[0];      // [4096*50] = 204800
  const float* W = (const float*)d_in[1];    // [128][100000]
  const float* b = (const float*)d_in[2];    // [128]
  float* out = (float*)d_out;                // [204800][128]
  const int n_lookups = in_sizes[0];

  const size_t wt_bytes = (size_t)NUM_EMB * DIM * sizeof(float);  // 51.2 MB
  if (ws_size >= wt_bytes) {
    float* WT = (float*)d_ws;
    transpose_bias_kernel<<<NUM_EMB / TILE_E, 256, 0, stream>>>(W, b, WT);
    const int blocks = (n_lookups + 7) / 8;
    gather_rows_kernel<<<blocks, 256, 0, stream>>>(idx, WT, out, n_lookups);
  } else {
    const long total = (long)n_lookups * DIM;
    int blocks = (int)((total + 255) / 256);
    if (blocks > 2048) blocks = 2048;
    direct_gather_kernel<<<blocks, 256, 0, stream>>>(idx, W, b, out, total);
  }
}

// Round 2
// 40.799 us; speedup vs baseline: 1.2706x; 1.2706x over previous
//
#include <hip/hip_runtime.h>

#define NUM_EMB 100000
#define DIM 128
#define TILE_E 32

typedef float f32x4 __attribute__((ext_vector_type(4)));
typedef unsigned short u16x4 __attribute__((ext_vector_type(4)));
typedef unsigned short u16x8 __attribute__((ext_vector_type(8)));

__device__ __forceinline__ unsigned short f32_to_bf16_rne(float f) {
  union { float f; unsigned int u; } c;
  c.f = f;
  unsigned int u = c.u;
  u += 0x7FFFu + ((u >> 16) & 1u);  // round-to-nearest-even
  return (unsigned short)(u >> 16);
}

__device__ __forceinline__ float bf16_to_f32(unsigned short h) {
  union { unsigned int u; float f; } c;
  c.u = ((unsigned int)h) << 16;
  return c.f;
}

// Pass 1: WT[e][d] = bf16(W[d][e] + b[d])   (fused bias, bf16 scratch)
// W: [DIM][NUM_EMB] f32 row-major, WT: [NUM_EMB][DIM] bf16 row-major.
// grid = NUM_EMB/TILE_E = 3125 blocks, 256 threads.
__global__ __launch_bounds__(256) void transpose_bias_bf16_kernel(
    const float* __restrict__ W, const float* __restrict__ b,
    unsigned short* __restrict__ WT) {
  __shared__ float tile[TILE_E][DIM + 1];  // +1 pad
  const int t = threadIdx.x;
  const int e0 = blockIdx.x * TILE_E;

  // Load phase: 128 d x 32 e = 1024 float4 (4 consecutive e per float4).
  // Wave: 8 lanes cover one 128B row segment; 8 d-rows per instruction.
#pragma unroll
  for (int k = 0; k < 4; ++k) {
    const int linear = k * 256 + t;  // 0..1023
    const int e4 = linear & 7;       // float4 slot within the 32-e span
    const int d = linear >> 3;       // 0..127
    const f32x4 v = *reinterpret_cast<const f32x4*>(
        &W[(size_t)d * NUM_EMB + e0 + e4 * 4]);
    const float bias = b[d];
    tile[e4 * 4 + 0][d] = v.x + bias;
    tile[e4 * 4 + 1][d] = v.y + bias;
    tile[e4 * 4 + 2][d] = v.z + bias;
    tile[e4 * 4 + 3][d] = v.w + bias;
  }
  __syncthreads();

  // Store phase: 32 e-rows x 16 chunks of 8 d = 512 u16x8 stores (16B each).
  // LDS reads: 8 consecutive floats/lane, contiguous across a 16-lane group.
#pragma unroll
  for (int k = 0; k < 2; ++k) {
    const int linear = k * 256 + t;  // 0..511
    const int e = linear >> 4;       // 0..31
    const int d0 = (linear & 15) * 8;
    u16x8 o;
#pragma unroll
    for (int j = 0; j < 8; ++j) o[j] = f32_to_bf16_rne(tile[e][d0 + j]);
    *reinterpret_cast<u16x8*>(&WT[(size_t)(e0 + e) * DIM + d0]) = o;
  }
}

// Pass 2: out[n][:] = f32(WT[idx[n]][:]) — 256B contiguous read per lookup,
// 512B contiguous (nontemporal) write. 32 lanes/lookup, 16 lookups/block.
__global__ __launch_bounds__(256) void gather_rows_bf16_kernel(
    const int* __restrict__ idx, const unsigned short* __restrict__ WT,
    float* __restrict__ out, int n_lookups) {
  const int t = threadIdx.x;
  const int g = t >> 5;   // lookup group 0..7
  const int q = t & 31;   // 4 elems per lane
#pragma unroll
  for (int i = 0; i < 2; ++i) {
    const int n = blockIdx.x * 16 + i * 8 + g;
    if (n >= n_lookups) return;
    const int e = idx[n];
    const u16x4 h =
        *reinterpret_cast<const u16x4*>(&WT[(size_t)e * DIM + q * 4]);
    f32x4 v;
    v.x = bf16_to_f32(h[0]);
    v.y = bf16_to_f32(h[1]);
    v.z = bf16_to_f32(h[2]);
    v.w = bf16_to_f32(h[3]);
    __builtin_nontemporal_store(
        v, reinterpret_cast<f32x4*>(&out[(size_t)n * DIM + q * 4]));
  }
}

// Fallback (ws too small): direct scattered gather, correct but slow.
__global__ __launch_bounds__(256) void direct_gather_kernel(
    const int* __restrict__ idx, const float* __restrict__ W,
    const float* __restrict__ b, float* __restrict__ out, long total) {
  long gid = (long)blockIdx.x * 256 + threadIdx.x;
  const long stride = (long)gridDim.x * 256;
  for (; gid < total; gid += stride) {
    const int d = (int)(gid & (DIM - 1));
    const long n = gid >> 7;
    out[gid] = W[(size_t)d * NUM_EMB + idx[n]] + b[d];
  }
}

extern "C" void kernel_launch(void* const* d_in, const int* in_sizes, int n_in,
                              void* d_out, int out_size, void* d_ws,
                              size_t ws_size, hipStream_t stream) {
  const int* idx = (const int*)d_in[0];    // [4096*50] = 204800
  const float* W = (const float*)d_in[1];  // [128][100000]
  const float* b = (const float*)d_in[2];  // [128]
  float* out = (float*)d_out;              // [204800][128]
  const int n_lookups = in_sizes[0];

  const size_t wt_bytes = (size_t)NUM_EMB * DIM * sizeof(unsigned short);
  if (ws_size >= wt_bytes) {
    unsigned short* WT = (unsigned short*)d_ws;
    transpose_bias_bf16_kernel<<<NUM_EMB / TILE_E, 256, 0, stream>>>(W, b, WT);
    const int blocks = (n_lookups + 15) / 16;
    gather_rows_bf16_kernel<<<blocks, 256, 0, stream>>>(idx, WT, out,
                                                        n_lookups);
  } else {
    const long total = (long)n_lookups * DIM;
    int blocks = (int)((total + 255) / 256);
    if (blocks > 2048) blocks = 2048;
    direct_gather_kernel<<<blocks, 256, 0, stream>>>(idx, W, b, out, total);
  }
}